// Round 12
// baseline (965.193 us; speedup 1.0000x reference)
//
#include <hip/hip_runtime.h>

#define N_NODES 50000
#define N_EDGES 400000
#define EQ      100000   // N_EDGES/4
#define N_TILES 25000    // N_EDGES/16
#define F_IN    128
#define F_EDGE  32
#define F       32
#define H       4
#define NHF     128   // H*F

#define SCAN_BLK 512
#define N_SCAN_BLKS ((N_NODES + SCAN_BLK - 1) / SCAN_BLK)   // 98

typedef __attribute__((ext_vector_type(8))) short bf16x8;
typedef __attribute__((ext_vector_type(4))) float f32x4;

// ---- bf16 helpers (RNE) ----
__device__ __forceinline__ float bf2f(unsigned short u) {
    return __uint_as_float(((unsigned)u) << 16);
}
__device__ __forceinline__ unsigned short f2bf(float f) {
    unsigned u = __float_as_uint(f);
    return (unsigned short)((u + 0x7FFFu + ((u >> 16) & 1u)) >> 16);
}
__device__ __forceinline__ ushort4 pack4(float4 v) {
    return make_ushort4(f2bf(v.x), f2bf(v.y), f2bf(v.z), f2bf(v.w));
}

// ---- atom_in = relu(x @ atom_w + atom_b) via MFMA ----
__global__ __launch_bounds__(256) void k_atom(const float* __restrict__ x,
                                              const float* __restrict__ w,
                                              const float* __restrict__ b,
                                              float* __restrict__ out) {
    __shared__ unsigned short Wt[NHF][F_IN + 8];    // [n][k], 34 KB
    for (int i = threadIdx.x; i < F_IN * NHF / 4; i += 256) {
        int k = i >> 5, ng = i & 31;
        float4 v = *(const float4*)(w + (size_t)k * NHF + ng * 4);
        Wt[ng * 4 + 0][k] = f2bf(v.x); Wt[ng * 4 + 1][k] = f2bf(v.y);
        Wt[ng * 4 + 2][k] = f2bf(v.z); Wt[ng * 4 + 3][k] = f2bf(v.w);
    }
    __syncthreads();
    int wv = threadIdx.x >> 6, lane = threadIdx.x & 63;
    int nn = lane & 15, kq = lane >> 4;
    int nbase = blockIdx.x * 64 + wv * 16;
    if (nbase >= N_NODES) return;
    f32x4 acc[8];
#pragma unroll
    for (int nt = 0; nt < 8; nt++) {
        float bv = b[nt * 16 + nn];
        acc[nt] = (f32x4){bv, bv, bv, bv};
    }
    const float* xr = x + (size_t)(nbase + nn) * F_IN + kq * 8;
#pragma unroll
    for (int kk = 0; kk < 4; kk++) {
        float4 v0 = *(const float4*)(xr + kk * 32);
        float4 v1 = *(const float4*)(xr + kk * 32 + 4);
        bf16x8 A;
        A[0] = (short)f2bf(v0.x); A[1] = (short)f2bf(v0.y);
        A[2] = (short)f2bf(v0.z); A[3] = (short)f2bf(v0.w);
        A[4] = (short)f2bf(v1.x); A[5] = (short)f2bf(v1.y);
        A[6] = (short)f2bf(v1.z); A[7] = (short)f2bf(v1.w);
        int kb = kk * 32 + kq * 8;
#pragma unroll
        for (int nt = 0; nt < 8; nt++) {
            bf16x8 B = *(const bf16x8*)(&Wt[nt * 16 + nn][kb]);
            acc[nt] = __builtin_amdgcn_mfma_f32_16x16x32_bf16(A, B, acc[nt], 0, 0, 0);
        }
    }
#pragma unroll
    for (int nt = 0; nt < 8; nt++) {
#pragma unroll
        for (int r = 0; r < 4; r++) {
            int row = nbase + kq * 4 + r;
            out[(size_t)row * NHF + nt * 16 + nn] = fmaxf(acc[nt][r], 0.f);
        }
    }
}

// ---- CSR build ----
__global__ __launch_bounds__(256) void k_hist(const int* __restrict__ dst,
                                              int* __restrict__ counts) {
    int e = blockIdx.x * 256 + threadIdx.x;
    if (e < N_EDGES) atomicAdd(counts + dst[e], 1);
}

__global__ __launch_bounds__(SCAN_BLK) void k_scan1(const int* __restrict__ counts,
        int* __restrict__ excl, int* __restrict__ bsum) {
    __shared__ int s[SCAN_BLK];
    int i = blockIdx.x * SCAN_BLK + threadIdx.x;
    int v = (i < N_NODES) ? counts[i] : 0;
    s[threadIdx.x] = v;
    __syncthreads();
    for (int d = 1; d < SCAN_BLK; d <<= 1) {
        int t = (threadIdx.x >= d) ? s[threadIdx.x - d] : 0;
        __syncthreads();
        s[threadIdx.x] += t;
        __syncthreads();
    }
    if (i < N_NODES) excl[i] = s[threadIdx.x] - v;
    if (threadIdx.x == SCAN_BLK - 1) bsum[blockIdx.x] = s[SCAN_BLK - 1];
}

__global__ __launch_bounds__(128) void k_scan2(int* __restrict__ bsum) {
    __shared__ int s[128];
    int v = (threadIdx.x < N_SCAN_BLKS) ? bsum[threadIdx.x] : 0;
    s[threadIdx.x] = v;
    __syncthreads();
    for (int d = 1; d < 128; d <<= 1) {
        int t = (threadIdx.x >= d) ? s[threadIdx.x - d] : 0;
        __syncthreads();
        s[threadIdx.x] += t;
        __syncthreads();
    }
    if (threadIdx.x < N_SCAN_BLKS) bsum[threadIdx.x] = s[threadIdx.x] - v;
}

__global__ __launch_bounds__(SCAN_BLK) void k_scan3(const int* __restrict__ excl,
        const int* __restrict__ bsum, int* __restrict__ row_start,
        int* __restrict__ cursor) {
    int i = blockIdx.x * SCAN_BLK + threadIdx.x;
    if (i < N_NODES) {
        int v = excl[i] + bsum[blockIdx.x];
        row_start[i] = v;
        cursor[i] = v;
    }
}

__global__ __launch_bounds__(256) void k_fill(const int* __restrict__ src,
        const int* __restrict__ dst, int* __restrict__ cursor,
        int* __restrict__ csr_e, int* __restrict__ srcp,
        int* __restrict__ inv_pos) {
    int e = blockIdx.x * 256 + threadIdx.x;
    if (e < N_EDGES) {
        int pos = atomicAdd(cursor + dst[e], 1);
        csr_e[pos] = e;
        srcp[pos] = src[e];
        inv_pos[e] = pos;
    }
}

// ---- edge_attr fp32 -> bf16 in MFMA A-fragment tile layout ----
__global__ __launch_bounds__(256) void k_cast(const float* __restrict__ edge_attr,
                                              unsigned short* __restrict__ eaA) {
    int t = blockIdx.x * 256 + threadIdx.x;
    int tile = t >> 6, lane = t & 63;
    int m = lane & 15, kq = lane >> 4;
    const float4* s = (const float4*)(edge_attr + ((size_t)tile * 16 + m) * F_EDGE + kq * 8);
    float4 v0 = s[0], v1 = s[1];
    *(ushort4*)(eaA + (size_t)t * 8)     = pack4(v0);
    *(ushort4*)(eaA + (size_t)t * 8 + 4) = pack4(v1);
}

// ---- MFMA edge linears: ea (csr order) + em ([q][j][f]) ----
__global__ __launch_bounds__(256) void k_edgepair(const unsigned short* __restrict__ eaA,
        const float* __restrict__ aew, const float* __restrict__ aeb,
        const float* __restrict__ mew, const float* __restrict__ meb,
        const int* __restrict__ inv_pos, unsigned short* __restrict__ ea_csr,
        unsigned short* __restrict__ emX) {
    __shared__ unsigned short stg[4][2][16][40];
    int wv = threadIdx.x >> 6, lane = threadIdx.x & 63;
    int nn = lane & 15, kq = lane >> 4;
    bf16x8 Ba0, Ba1, Bm0, Bm1;
#pragma unroll
    for (int j = 0; j < 8; j++) {
        int k = kq * 8 + j;
        Ba0[j] = (short)f2bf(aew[k * F + nn]);
        Ba1[j] = (short)f2bf(aew[k * F + 16 + nn]);
        Bm0[j] = (short)f2bf(mew[k * F + nn]);
        Bm1[j] = (short)f2bf(mew[k * F + 16 + nn]);
    }
    float ba0 = aeb[nn], ba1 = aeb[16 + nn];
    float bm0 = meb[nn], bm1 = meb[16 + nn];
    for (int tt = 0; tt < 4; tt++) {
        int tile = blockIdx.x * 16 + wv * 4 + tt;
        if (tile >= N_TILES) break;
        bf16x8 A = *(const bf16x8*)(eaA + ((size_t)tile * 64 + lane) * 8);
        f32x4 c0 = {ba0, ba0, ba0, ba0};
        f32x4 c1 = {ba1, ba1, ba1, ba1};
        f32x4 c2 = {bm0, bm0, bm0, bm0};
        f32x4 c3 = {bm1, bm1, bm1, bm1};
        c0 = __builtin_amdgcn_mfma_f32_16x16x32_bf16(A, Ba0, c0, 0, 0, 0);
        c1 = __builtin_amdgcn_mfma_f32_16x16x32_bf16(A, Ba1, c1, 0, 0, 0);
        c2 = __builtin_amdgcn_mfma_f32_16x16x32_bf16(A, Bm0, c2, 0, 0, 0);
        c3 = __builtin_amdgcn_mfma_f32_16x16x32_bf16(A, Bm1, c3, 0, 0, 0);
#pragma unroll
        for (int r = 0; r < 4; r++) {
            int row = kq * 4 + r;
            stg[wv][0][row][nn]      = f2bf(c0[r]);
            stg[wv][0][row][nn + 16] = f2bf(c1[r]);
            stg[wv][1][row][nn]      = f2bf(c2[r]);
            stg[wv][1][row][nn + 16] = f2bf(c3[r]);
        }
        __builtin_amdgcn_s_waitcnt(0);
#pragma unroll
        for (int it = 0; it < 2; it++) {
            int rg = (it == 0) ? (lane >> 2) : (16 + (lane >> 2));
            int seg = lane & 3;
            int mat = rg >> 4, r = rg & 15;
            int e = tile * 16 + r;
            uint4 v = *(uint4*)&stg[wv][mat][r][seg * 8];
            if (mat == 0) {
                int p = inv_pos[e];
                *(uint4*)(ea_csr + (size_t)p * F + seg * 8) = v;
            } else {
                int q = e % EQ, j = e / EQ;
                *(uint4*)(emX + (size_t)q * NHF + j * F + seg * 8) = v;
            }
        }
    }
}

// ---- xs,xd,xm = h @ {Ws,Wd,Wm} + b -> bf16 outputs ----
__global__ __launch_bounds__(256) void k_nodelin3(const float* __restrict__ h,
        const float* __restrict__ ws, const float* __restrict__ bs,
        const float* __restrict__ wd, const float* __restrict__ bd,
        const float* __restrict__ wm, const float* __restrict__ bm,
        unsigned short* __restrict__ xs, unsigned short* __restrict__ xd,
        unsigned short* __restrict__ xm) {
    __shared__ float Ws[F * F], Wd[F * F], Wm[F * F];
    __shared__ float hrt[F][64];
    for (int i = threadIdx.x; i < F * F; i += 256) {
        Ws[i] = ws[i]; Wd[i] = wd[i]; Wm[i] = wm[i];
    }
    int rbase = blockIdx.x * 64;
    for (int i = threadIdx.x; i < 512; i += 256) {
        int row = i >> 3, kq = i & 7;
        float4 v = *(const float4*)(h + (size_t)(rbase + row) * F + kq * 4);
        hrt[kq * 4 + 0][row] = v.x; hrt[kq * 4 + 1][row] = v.y;
        hrt[kq * 4 + 2][row] = v.z; hrt[kq * 4 + 3][row] = v.w;
    }
    __syncthreads();
    int rl = threadIdx.x >> 2;
    int jg = threadIdx.x & 3;
    float4 s0 = *(const float4*)(bs + jg * 8), s1 = *(const float4*)(bs + jg * 8 + 4);
    float4 d0 = *(const float4*)(bd + jg * 8), d1 = *(const float4*)(bd + jg * 8 + 4);
    float4 m0 = *(const float4*)(bm + jg * 8), m1 = *(const float4*)(bm + jg * 8 + 4);
    for (int k = 0; k < F; k++) {
        float hv = hrt[k][rl];
        float4 a, b2;
        a = *(const float4*)(Ws + k * F + jg * 8); b2 = *(const float4*)(Ws + k * F + jg * 8 + 4);
        s0.x += hv * a.x; s0.y += hv * a.y; s0.z += hv * a.z; s0.w += hv * a.w;
        s1.x += hv * b2.x; s1.y += hv * b2.y; s1.z += hv * b2.z; s1.w += hv * b2.w;
        a = *(const float4*)(Wd + k * F + jg * 8); b2 = *(const float4*)(Wd + k * F + jg * 8 + 4);
        d0.x += hv * a.x; d0.y += hv * a.y; d0.z += hv * a.z; d0.w += hv * a.w;
        d1.x += hv * b2.x; d1.y += hv * b2.y; d1.z += hv * b2.z; d1.w += hv * b2.w;
        a = *(const float4*)(Wm + k * F + jg * 8); b2 = *(const float4*)(Wm + k * F + jg * 8 + 4);
        m0.x += hv * a.x; m0.y += hv * a.y; m0.z += hv * a.z; m0.w += hv * a.w;
        m1.x += hv * b2.x; m1.y += hv * b2.y; m1.z += hv * b2.z; m1.w += hv * b2.w;
    }
    size_t o = (size_t)(rbase + rl) * F + jg * 8;
    *(ushort4*)(xs + o) = pack4(s0); *(ushort4*)(xs + o + 4) = pack4(s1);
    *(ushort4*)(xd + o) = pack4(d0); *(ushort4*)(xd + o + 4) = pack4(d1);
    *(ushort4*)(xm + o) = pack4(m0); *(ushort4*)(xm + o + 4) = pack4(m1);
}

// ---- fused attention: one wave per dst node; logits + joint softmax ----
__global__ __launch_bounds__(256) void k_attn(const unsigned short* __restrict__ ea_csr,
        const unsigned short* __restrict__ xs, const unsigned short* __restrict__ xd,
        const int* __restrict__ srcp, const int* __restrict__ row_start,
        const int* __restrict__ counts, const int* __restrict__ csr_e,
        const float* __restrict__ dw, const float* __restrict__ db,
        float* __restrict__ alphaT) {
    __shared__ float lg[4][512];
    int wv = threadIdx.x >> 6, lane = threadIdx.x & 63;
    int n = blockIdx.x * 4 + wv;
    if (n >= N_NODES) return;
    int start = row_start[n];
    int items = counts[n] * 4;
    float4 wreg[8];
#pragma unroll
    for (int q = 0; q < 8; q++) wreg[q] = *(const float4*)(dw + q * 4);
    float dbv = db[0];
    const unsigned short* xsr = xs + (size_t)n * NHF;
    float m = -1e30f;
    for (int i = lane; i < items; i += 64) {
        int ii = i >> 2, hh = i & 3;
        int p = start + ii;
        int s = srcp[p];
        const unsigned short* ear = ea_csr + (size_t)p * F;
        const unsigned short* xsh = xsr + hh * F;
        const unsigned short* xdh = xd + (size_t)s * NHF + hh * F;
        float acc = 0.f;
#pragma unroll
        for (int q = 0; q < 8; q++) {
            ushort4 ue = *(const ushort4*)(ear + q * 4);
            ushort4 ua = *(const ushort4*)(xsh + q * 4);
            ushort4 ub = *(const ushort4*)(xdh + q * 4);
            acc += fmaxf(bf2f(ua.x) + bf2f(ub.x) + bf2f(ue.x), 0.f) * wreg[q].x;
            acc += fmaxf(bf2f(ua.y) + bf2f(ub.y) + bf2f(ue.y), 0.f) * wreg[q].y;
            acc += fmaxf(bf2f(ua.z) + bf2f(ub.z) + bf2f(ue.z), 0.f) * wreg[q].z;
            acc += fmaxf(bf2f(ua.w) + bf2f(ub.w) + bf2f(ue.w), 0.f) * wreg[q].w;
        }
        float l = acc + dbv;
        lg[wv][i] = l;
        m = fmaxf(m, l);
    }
#pragma unroll
    for (int d = 1; d < 64; d <<= 1) m = fmaxf(m, __shfl_xor(m, d));
    float ssum = 0.f;
    for (int i = lane; i < items; i += 64) ssum += __expf(lg[wv][i] - m);
#pragma unroll
    for (int d = 1; d < 64; d <<= 1) ssum += __shfl_xor(ssum, d);
    float inv = 1.f / (ssum + 1e-8f);
    for (int i = lane; i < items; i += 64) {
        int ii = i >> 2, hh = i & 3;
        int e = csr_e[start + ii];
        float a = __expf(lg[wv][i] - m) * inv;
        alphaT[(size_t)(e % EQ) * 16 + hh * 4 + (e / EQ)] = a;
    }
}

// ---- q-major message build ----
__global__ __launch_bounds__(256) void k_msgq(const float* __restrict__ alphaT,
        const unsigned short* __restrict__ emX, const unsigned short* __restrict__ xm,
        const int* __restrict__ dst, const int* __restrict__ inv_pos,
        unsigned short* __restrict__ ems_csr) {
    int g = blockIdx.x * 8 + (threadIdx.x >> 5);
    if (g >= EQ) return;
    int f = threadIdx.x & 31;
    const float4* a4 = (const float4*)(alphaT + (size_t)g * 16);
    float4 ac[4] = {a4[0], a4[1], a4[2], a4[3]};
    int4 dj = make_int4(dst[g], dst[g + EQ], dst[g + 2 * EQ], dst[g + 3 * EQ]);
    float out[4] = {0.f, 0.f, 0.f, 0.f};
#pragma unroll
    for (int j = 0; j < 4; j++) {
        int d = (j == 0) ? dj.x : (j == 1) ? dj.y : (j == 2) ? dj.z : dj.w;
        float emv = bf2f(emX[(size_t)g * NHF + j * F + f]);
        const unsigned short* xr = xm + (size_t)d * NHF + f;
#pragma unroll
        for (int c = 0; c < 4; c++) {
            float a = (j == 0) ? ac[c].x : (j == 1) ? ac[c].y
                    : (j == 2) ? ac[c].z : ac[c].w;
            out[c] += a * (bf2f(xr[c * F]) + emv);
        }
    }
    const int4 pos = *(const int4*)(inv_pos + (size_t)g * 4);
#pragma unroll
    for (int c = 0; c < 4; c++) {
        int p = (c == 0) ? pos.x : (c == 1) ? pos.y : (c == 2) ? pos.z : pos.w;
        ems_csr[(size_t)p * F + f] = f2bf(out[c]);
    }
}

// ---- shared core for combine: matvec + message pull, returns v0/v1 ----
__device__ __forceinline__ void combine_core(
        const unsigned short* __restrict__ ems_csr, const int* __restrict__ row_start,
        const int* __restrict__ counts, const float* __restrict__ atom_in,
        const float* W, float hrt[F][64], const float* __restrict__ bn,
        int rbase, float4& v0, float4& v1, size_t& idx) {
    int rl = threadIdx.x >> 2;
    int jg = threadIdx.x & 3;
    float4 a0 = *(const float4*)(bn + jg * 8);
    float4 a1 = *(const float4*)(bn + jg * 8 + 4);
    for (int k = 0; k < F; k++) {
        float hv = hrt[k][rl];
        float4 w0 = *(const float4*)(W + k * F + jg * 8);
        float4 w1 = *(const float4*)(W + k * F + jg * 8 + 4);
        a0.x += hv * w0.x; a0.y += hv * w0.y; a0.z += hv * w0.z; a0.w += hv * w0.w;
        a1.x += hv * w1.x; a1.y += hv * w1.y; a1.z += hv * w1.z; a1.w += hv * w1.w;
    }
    int m = rbase + rl;
    float4 g0 = make_float4(0.f, 0.f, 0.f, 0.f);
    float4 g1 = make_float4(0.f, 0.f, 0.f, 0.f);
    if (m < N_NODES) {
        int st = row_start[m], deg = counts[m];
        const unsigned short* er = ems_csr + (size_t)st * F + jg * 8;
        int p = 0;
        for (; p + 2 <= deg; p += 2) {
            ushort4 u0 = *(const ushort4*)(er);
            ushort4 u1 = *(const ushort4*)(er + 4);
            ushort4 w0 = *(const ushort4*)(er + F);
            ushort4 w1 = *(const ushort4*)(er + F + 4);
            g0.x += bf2f(u0.x) + bf2f(w0.x); g0.y += bf2f(u0.y) + bf2f(w0.y);
            g0.z += bf2f(u0.z) + bf2f(w0.z); g0.w += bf2f(u0.w) + bf2f(w0.w);
            g1.x += bf2f(u1.x) + bf2f(w1.x); g1.y += bf2f(u1.y) + bf2f(w1.y);
            g1.z += bf2f(u1.z) + bf2f(w1.z); g1.w += bf2f(u1.w) + bf2f(w1.w);
            er += 2 * F;
        }
        if (p < deg) {
            ushort4 u0 = *(const ushort4*)(er);
            ushort4 u1 = *(const ushort4*)(er + 4);
            g0.x += bf2f(u0.x); g0.y += bf2f(u0.y);
            g0.z += bf2f(u0.z); g0.w += bf2f(u0.w);
            g1.x += bf2f(u1.x); g1.y += bf2f(u1.y);
            g1.z += bf2f(u1.z); g1.w += bf2f(u1.w);
        }
    }
    idx = (size_t)m * F + jg * 8;
    float4 t0 = *(const float4*)(atom_in + idx);
    float4 t1 = *(const float4*)(atom_in + idx + 4);
    v0.x = fmaxf(a0.x + g0.x + t0.x, 0.f); v0.y = fmaxf(a0.y + g0.y + t0.y, 0.f);
    v0.z = fmaxf(a0.z + g0.z + t0.z, 0.f); v0.w = fmaxf(a0.w + g0.w + t0.w, 0.f);
    v1.x = fmaxf(a1.x + g1.x + t1.x, 0.f); v1.y = fmaxf(a1.y + g1.y + t1.y, 0.f);
    v1.z = fmaxf(a1.z + g1.z + t1.z, 0.f); v1.w = fmaxf(a1.w + g1.w + t1.w, 0.f);
}

__device__ __forceinline__ void combine_stage(const float* __restrict__ h,
        const float* __restrict__ wn, float* W, float hrt[F][64], int rbase) {
    for (int i = threadIdx.x; i < F * F; i += 256) W[i] = wn[i];
    for (int i = threadIdx.x; i < 512; i += 256) {
        int row = i >> 3, kq = i & 7;
        float4 v = *(const float4*)(h + (size_t)(rbase + row) * F + kq * 4);
        hrt[kq * 4 + 0][row] = v.x; hrt[kq * 4 + 1][row] = v.y;
        hrt[kq * 4 + 2][row] = v.z; hrt[kq * 4 + 3][row] = v.w;
    }
    __syncthreads();
}

// ---- layer-0 combine: writes hout only. Register-capped for occupancy. ----
__global__ __launch_bounds__(256, 4) void k_combine0(const float* __restrict__ h,
        const unsigned short* __restrict__ ems_csr, const int* __restrict__ row_start,
        const int* __restrict__ counts, const float* __restrict__ atom_in,
        const float* __restrict__ wn, const float* __restrict__ bn,
        float* __restrict__ hout) {
    __shared__ float W[F * F];
    __shared__ float hrt[F][64];
    int rbase = blockIdx.x * 64;
    combine_stage(h, wn, W, hrt, rbase);
    float4 v0, v1; size_t idx;
    combine_core(ems_csr, row_start, counts, atom_in, W, hrt, bn, rbase,
                 v0, v1, idx);
    *(float4*)(hout + idx) = v0;
    *(float4*)(hout + idx + 4) = v1;
}

// ---- final combine: head-mean epilogue only. ----
__global__ __launch_bounds__(256, 4) void k_combine1(const float* __restrict__ h,
        const unsigned short* __restrict__ ems_csr, const int* __restrict__ row_start,
        const int* __restrict__ counts, const float* __restrict__ atom_in,
        const float* __restrict__ wn, const float* __restrict__ bn,
        float* __restrict__ final_out) {
    __shared__ float W[F * F];
    __shared__ float hrt[F][64];
    __shared__ float smv[64][F + 4];
    int rbase = blockIdx.x * 64;
    combine_stage(h, wn, W, hrt, rbase);
    float4 v0, v1; size_t idx;
    combine_core(ems_csr, row_start, counts, atom_in, W, hrt, bn, rbase,
                 v0, v1, idx);
    int rl = threadIdx.x >> 2, jg = threadIdx.x & 3;
    *(float4*)(&smv[rl][jg * 8]) = v0;
    *(float4*)(&smv[rl][jg * 8 + 4]) = v1;
    __syncthreads();
#pragma unroll
    for (int it = 0; it < 2; it++) {
        int oi = threadIdx.x + it * 256;
        int nl = oi >> 5, f = oi & 31;
        float o = 0.25f * (smv[nl * 4 + 0][f] + smv[nl * 4 + 1][f] +
                           smv[nl * 4 + 2][f] + smv[nl * 4 + 3][f]);
        final_out[((size_t)(rbase >> 2) + nl) * F + f] = o;
    }
}

extern "C" void kernel_launch(void* const* d_in, const int* in_sizes, int n_in,
                              void* d_out, int out_size, void* d_ws, size_t ws_size,
                              hipStream_t stream) {
    const float* x         = (const float*)d_in[0];
    const float* edge_attr = (const float*)d_in[1];
    const int*   eidx      = (const int*)d_in[2];
    const int*   src       = eidx;
    const int*   dst       = eidx + N_EDGES;
    const float* atom_w    = (const float*)d_in[3];
    const float* atom_b    = (const float*)d_in[4];
    const float* asw = (const float*)d_in[5],  *asb = (const float*)d_in[6];
    const float* adw = (const float*)d_in[7],  *adb = (const float*)d_in[8];
    const float* aew = (const float*)d_in[9],  *aeb = (const float*)d_in[10];
    const float* dww = (const float*)d_in[11], *dwb = (const float*)d_in[12];
    const float* mdw = (const float*)d_in[13], *mdb = (const float*)d_in[14];
    const float* mew = (const float*)d_in[15], *meb = (const float*)d_in[16];
    const float* wnw = (const float*)d_in[17], *wnb = (const float*)d_in[18];
    float* out = (float*)d_out;

    float* ws = (float*)d_ws;
    size_t off = 0;
    float* atom_in = ws + off; off += (size_t)N_NODES * NHF;
    float* hbuf    = ws + off; off += (size_t)N_NODES * NHF;
    unsigned short* xs_bf  = (unsigned short*)(ws + off); off += (size_t)N_NODES * NHF / 2;
    unsigned short* xd_bf  = (unsigned short*)(ws + off); off += (size_t)N_NODES * NHF / 2;
    unsigned short* xm_bf  = (unsigned short*)(ws + off); off += (size_t)N_NODES * NHF / 2;
    unsigned short* ea_csr = (unsigned short*)(ws + off); off += (size_t)N_EDGES * F / 2;
    unsigned short* emX    = (unsigned short*)(ws + off); off += (size_t)N_EDGES * F / 2;
    unsigned short* ems    = (unsigned short*)(ws + off); off += (size_t)N_EDGES * F / 2;
    unsigned short* eaA    = (unsigned short*)(ws + off); off += (size_t)N_EDGES * F_EDGE / 2;
    float* alphaT  = ws + off; off += (size_t)N_EDGES * H;
    int* counts    = (int*)(ws + off); off += N_NODES;
    int* row_start = (int*)(ws + off); off += N_NODES;
    int* cursor    = (int*)(ws + off); off += N_NODES;
    int* excl      = (int*)(ws + off); off += N_NODES;
    int* bsum      = (int*)(ws + off); off += 128;
    int* csr_e     = (int*)(ws + off); off += N_EDGES;
    int* srcp      = (int*)(ws + off); off += N_EDGES;
    int* inv_pos   = (int*)(ws + off); off += N_EDGES;

    // ---- CSR build (dst is layer-invariant) ----
    hipMemsetAsync(counts, 0, N_NODES * sizeof(int), stream);
    k_hist <<<(N_EDGES + 255) / 256, 256, 0, stream>>>(dst, counts);
    k_scan1<<<N_SCAN_BLKS, SCAN_BLK, 0, stream>>>(counts, excl, bsum);
    k_scan2<<<1, 128, 0, stream>>>(bsum);
    k_scan3<<<N_SCAN_BLKS, SCAN_BLK, 0, stream>>>(excl, bsum, row_start, cursor);
    k_fill <<<(N_EDGES + 255) / 256, 256, 0, stream>>>(src, dst, cursor, csr_e,
                                                       srcp, inv_pos);
    k_cast <<<(N_TILES * 64) / 256, 256, 0, stream>>>(edge_attr, eaA);

    k_atom<<<(N_NODES + 63) / 64, 256, 0, stream>>>(x, atom_w, atom_b, atom_in);

    for (int l = 0; l < 2; l++) {
        const float* hin  = (l == 0) ? atom_in : hbuf;
        int is_final = (l == 1);
        k_nodelin3<<<(N_NODES * H) / 64, 256, 0, stream>>>(
            hin, asw + l * F * F, asb + l * F, adw + l * F * F, adb + l * F,
            mdw + l * F * F, mdb + l * F, xs_bf, xd_bf, xm_bf);
        k_edgepair<<<(N_TILES + 15) / 16, 256, 0, stream>>>(
            eaA, aew + l * F_EDGE * F, aeb + l * F,
            mew + l * F_EDGE * F, meb + l * F, inv_pos, ea_csr, emX);
        k_attn<<<(N_NODES + 3) / 4, 256, 0, stream>>>(
            ea_csr, xs_bf, xd_bf, srcp, row_start, counts, csr_e,
            dww + l * F, dwb + l, alphaT);
        k_msgq<<<(EQ + 7) / 8, 256, 0, stream>>>(alphaT, emX, xm_bf, dst,
                                                 inv_pos, ems);
        if (!is_final) {
            k_combine0<<<(N_NODES * H) / 64, 256, 0, stream>>>(
                hin, ems, row_start, counts, atom_in, wnw + l * F * F,
                wnb + l * F, hbuf);
        } else {
            k_combine1<<<(N_NODES * H) / 64, 256, 0, stream>>>(
                hin, ems, row_start, counts, atom_in, wnw + l * F * F,
                wnb + l * F, out);
        }
    }
}